// Round 1
// baseline (796.604 us; speedup 1.0000x reference)
//
#include <hip/hip_runtime.h>
#include <type_traits>

// PerceiverAttentionCA on MI355X (gfx950).
// b=2, n1=n2=2048, DIM=3072, KV_DIM=2048, HEADS=16, DHEAD=128, INNER=2048.
// Strategy: bf16 MFMA everywhere (fp32 accumulate), fp32 softmax state.
// Round 1: correctness-first; plain LDS staging (no global_load_lds yet).

using u16 = unsigned short;
using u32 = unsigned int;
typedef __attribute__((ext_vector_type(8))) short short8;   // 8 x bf16 bits (4 VGPRs)
typedef __attribute__((ext_vector_type(4))) float floatx4;  // MFMA accumulator

__device__ inline u16 f2bf(float f) {
  u32 u = __float_as_uint(f);
  u32 r = (u + 0x7FFFu + ((u >> 16) & 1u)) >> 16;   // round-to-nearest-even
  return (u16)r;
}

// ---------------------------------------------------------------------------
// LayerNorm + cast to bf16.  One block (256 thr) per row.  L in {2048, 3072}.
// ---------------------------------------------------------------------------
template <int L>
__global__ __launch_bounds__(256) void ln_cast(const float* __restrict__ in,
                                               const float* __restrict__ gw,
                                               const float* __restrict__ bw,
                                               u16* __restrict__ out) {
  constexpr int C4 = L / 1024;  // float4 chunks per thread
  const int row = blockIdx.x;
  const int t = threadIdx.x;
  const float* rp = in + (size_t)row * L;
  float4 v[C4];
  float s = 0.f, ss = 0.f;
#pragma unroll
  for (int c = 0; c < C4; ++c) {
    v[c] = *(const float4*)(rp + (c * 256 + t) * 4);
    s += v[c].x + v[c].y + v[c].z + v[c].w;
    ss += v[c].x * v[c].x + v[c].y * v[c].y + v[c].z * v[c].z + v[c].w * v[c].w;
  }
#pragma unroll
  for (int off = 32; off > 0; off >>= 1) {
    s += __shfl_down(s, off);
    ss += __shfl_down(ss, off);
  }
  __shared__ float red[8];
  const int wave = t >> 6, lane = t & 63;
  if (lane == 0) { red[wave] = s; red[4 + wave] = ss; }
  __syncthreads();
  const float tot = red[0] + red[1] + red[2] + red[3];
  const float tss = red[4] + red[5] + red[6] + red[7];
  const float mu = tot * (1.f / L);
  const float rstd = rsqrtf(tss * (1.f / L) - mu * mu + 1e-5f);
  u16* op = out + (size_t)row * L;
#pragma unroll
  for (int c = 0; c < C4; ++c) {
    const int base = (c * 256 + t) * 4;
    float4 gv = *(const float4*)(gw + base);
    float4 bv = *(const float4*)(bw + base);
    u32 p0 = (u32)f2bf((v[c].x - mu) * rstd * gv.x + bv.x) |
             ((u32)f2bf((v[c].y - mu) * rstd * gv.y + bv.y) << 16);
    u32 p1 = (u32)f2bf((v[c].z - mu) * rstd * gv.z + bv.z) |
             ((u32)f2bf((v[c].w - mu) * rstd * gv.w + bv.w) << 16);
    uint2 pk; pk.x = p0; pk.y = p1;
    *(uint2*)(op + base) = pk;
  }
}

// ---------------------------------------------------------------------------
// Transpose + cast: fp32 in (R x C) -> bf16 out (C x R).  Block (32,8).
// ---------------------------------------------------------------------------
__global__ __launch_bounds__(256) void transpose_cast(const float* __restrict__ in,
                                                      u16* __restrict__ out,
                                                      int R, int C) {
  __shared__ u16 tile[32][33];
  const int c0 = blockIdx.x * 32, r0 = blockIdx.y * 32;
  const int x = threadIdx.x, y = threadIdx.y;
#pragma unroll
  for (int j = 0; j < 4; ++j)
    tile[y + 8 * j][x] = f2bf(in[(size_t)(r0 + y + 8 * j) * C + c0 + x]);
  __syncthreads();
#pragma unroll
  for (int j = 0; j < 4; ++j)
    out[(size_t)(c0 + y + 8 * j) * R + r0 + x] = tile[x][y + 8 * j];
}

// ---------------------------------------------------------------------------
// Extract+transpose V from kv buffer: per (b,h): (n1 x 128, row stride 4096)
// -> vT (b,h,128,2048) contiguous.  Block (32,8), grid (4, 64, 32).
// ---------------------------------------------------------------------------
__global__ __launch_bounds__(256) void transpose_v(const u16* __restrict__ kvb,
                                                   u16* __restrict__ vT) {
  __shared__ u16 tile[32][33];
  const int bh = blockIdx.z, b = bh >> 4, h = bh & 15;
  const u16* src = kvb + (size_t)b * 2048 * 4096 + 2048 + h * 128;
  u16* dst = vT + (size_t)bh * 128 * 2048;
  const int d0 = blockIdx.x * 32, n0 = blockIdx.y * 32;
  const int x = threadIdx.x, y = threadIdx.y;
#pragma unroll
  for (int j = 0; j < 4; ++j)
    tile[y + 8 * j][x] = src[(size_t)(n0 + y + 8 * j) * 4096 + d0 + x];
  __syncthreads();
#pragma unroll
  for (int j = 0; j < 4; ++j)
    dst[(size_t)(d0 + y + 8 * j) * 2048 + n0 + x] = tile[x][y + 8 * j];
}

// ---------------------------------------------------------------------------
// GEMM  C(MxN) = A(MxK) * Bt(NxK)^T, bf16 in, fp32 acc, OutT out.
// 128x128 tile, BK=32, 4 waves of 64x64 (4x4 mfma_f32_16x16x32_bf16).
// Verified layouts: A/B frag [lane&15][quad*8+j]; C/D col=lane&15,row=quad*4+r.
// ---------------------------------------------------------------------------
template <typename OutT>
__global__ __launch_bounds__(256) void gemm_bt(const u16* __restrict__ A,
                                               const u16* __restrict__ Bt,
                                               OutT* __restrict__ C,
                                               int M, int N, int K) {
  __shared__ u16 As[128][40];  // +8 pad
  __shared__ u16 Bs[128][40];
  const int tid = threadIdx.x;
  const int wave = tid >> 6, lane = tid & 63, l16 = lane & 15, quad = lane >> 4;
  const int wm = (wave >> 1) * 64, wn = (wave & 1) * 64;
  const long m0 = (long)blockIdx.y * 128, n0 = (long)blockIdx.x * 128;
  const int sr = tid >> 2;         // 0..63
  const int sc = (tid & 3) * 8;    // 0,8,16,24
  const u16* Ag = A + (m0 + sr) * (long)K + sc;
  const u16* Bg = Bt + (n0 + sr) * (long)K + sc;

  const floatx4 fz = {0.f, 0.f, 0.f, 0.f};
  floatx4 acc[4][4];
#pragma unroll
  for (int i = 0; i < 4; ++i)
#pragma unroll
    for (int j = 0; j < 4; ++j) acc[i][j] = fz;

  for (int k0 = 0; k0 < K; k0 += 32) {
    __syncthreads();
    *(uint4*)&As[sr][sc]      = *(const uint4*)(Ag + k0);
    *(uint4*)&As[sr + 64][sc] = *(const uint4*)(Ag + 64L * K + k0);
    *(uint4*)&Bs[sr][sc]      = *(const uint4*)(Bg + k0);
    *(uint4*)&Bs[sr + 64][sc] = *(const uint4*)(Bg + 64L * K + k0);
    __syncthreads();
    short8 a[4], b[4];
#pragma unroll
    for (int i = 0; i < 4; ++i) a[i] = *(const short8*)&As[wm + i * 16 + l16][quad * 8];
#pragma unroll
    for (int j = 0; j < 4; ++j) b[j] = *(const short8*)&Bs[wn + j * 16 + l16][quad * 8];
#pragma unroll
    for (int i = 0; i < 4; ++i)
#pragma unroll
      for (int j = 0; j < 4; ++j)
        acc[i][j] = __builtin_amdgcn_mfma_f32_16x16x32_bf16(a[i], b[j], acc[i][j], 0, 0, 0);
  }

#pragma unroll
  for (int i = 0; i < 4; ++i)
#pragma unroll
    for (int r = 0; r < 4; ++r) {
      const long row = m0 + wm + i * 16 + quad * 4 + r;
#pragma unroll
      for (int j = 0; j < 4; ++j) {
        const long col = n0 + wn + j * 16 + l16;
        if constexpr (std::is_same<OutT, float>::value)
          C[row * N + col] = acc[i][j][r];
        else
          C[row * N + col] = f2bf(acc[i][j][r]);
      }
    }
}

// ---------------------------------------------------------------------------
// Flash attention.  Grid (n2/64, b*h).  Block 256 = 4 waves, 16 q-rows/wave.
// Q frags in registers; KV tiles of 128 through one shared LDS buffer (K then
// V^T); P via LDS round-trip (C-layout -> A-layout).  fp32 online softmax.
// ---------------------------------------------------------------------------
__global__ __launch_bounds__(256) void flash_attn(const u16* __restrict__ Q,
                                                  const u16* __restrict__ KV,
                                                  const u16* __restrict__ VT,
                                                  u16* __restrict__ O) {
  __shared__ u16 KVs[128][136];  // K tile [kv][d] then V^T tile [d][kv]
  __shared__ u16 Ps[64][136];    // P tile [q][kv]
  const int tid = threadIdx.x;
  const int wave = tid >> 6, lane = tid & 63, l16 = lane & 15, quad = lane >> 4;
  const int bh = blockIdx.y, b = bh >> 4, h = bh & 15;
  const u16* Qb = Q + (size_t)b * 2048 * 2048 + h * 128;
  const u16* Kb = KV + (size_t)b * 2048 * 4096 + h * 128;
  const u16* Vb = VT + (size_t)bh * 128 * 2048;
  u16* Ob = O + (size_t)b * 2048 * 2048 + h * 128;
  const int qr0 = blockIdx.x * 64 + wave * 16;

  short8 qf[4];
#pragma unroll
  for (int kd = 0; kd < 4; ++kd)
    qf[kd] = *(const short8*)&Qb[(size_t)(qr0 + l16) * 2048 + kd * 32 + quad * 8];

  const floatx4 fz = {0.f, 0.f, 0.f, 0.f};
  floatx4 of[8];
  float m_r[4], l_r[4];
#pragma unroll
  for (int j = 0; j < 8; ++j) of[j] = fz;
#pragma unroll
  for (int r = 0; r < 4; ++r) { m_r[r] = -1e30f; l_r[r] = 0.f; }

  const int sr = tid >> 1, sh = (tid & 1) * 64;
  const float sc = 0.08838834764831845f;  // 1/sqrt(128)

  for (int kt = 0; kt < 16; ++kt) {
    const int kv0 = kt * 128;
    __syncthreads();  // prev PV done with KVs
#pragma unroll
    for (int i = 0; i < 8; ++i)
      *(uint4*)&KVs[sr][sh + i * 8] =
          *(const uint4*)&Kb[(size_t)(kv0 + sr) * 4096 + sh + i * 8];
    __syncthreads();

    // S = Q K^T  (16 x 128 per wave)
    floatx4 sacc[8];
#pragma unroll
    for (int j = 0; j < 8; ++j) sacc[j] = fz;
#pragma unroll
    for (int jn = 0; jn < 8; ++jn)
#pragma unroll
      for (int kd = 0; kd < 4; ++kd) {
        short8 kb = *(const short8*)&KVs[jn * 16 + l16][kd * 32 + quad * 8];
        sacc[jn] = __builtin_amdgcn_mfma_f32_16x16x32_bf16(qf[kd], kb, sacc[jn], 0, 0, 0);
      }

    // online softmax (rows quad*4+r, cols jn*16+l16)
#pragma unroll
    for (int r = 0; r < 4; ++r) {
      float mx = sacc[0][r];
#pragma unroll
      for (int jn = 1; jn < 8; ++jn) mx = fmaxf(mx, sacc[jn][r]);
#pragma unroll
      for (int off = 8; off > 0; off >>= 1) mx = fmaxf(mx, __shfl_xor(mx, off, 16));
      const float mnew = fmaxf(m_r[r], sc * mx);
      const float alpha = __expf(m_r[r] - mnew);
      float rs = 0.f;
      const int prow = wave * 16 + quad * 4 + r;
#pragma unroll
      for (int jn = 0; jn < 8; ++jn) {
        float p = __expf(sc * sacc[jn][r] - mnew);
        rs += p;
        Ps[prow][jn * 16 + l16] = f2bf(p);
      }
#pragma unroll
      for (int off = 8; off > 0; off >>= 1) rs += __shfl_xor(rs, off, 16);
      l_r[r] = alpha * l_r[r] + rs;
      m_r[r] = mnew;
#pragma unroll
      for (int jd = 0; jd < 8; ++jd) of[jd][r] = of[jd][r] * alpha;
    }

    __syncthreads();  // all waves done reading K; P writes visible
#pragma unroll
    for (int i = 0; i < 8; ++i)
      *(uint4*)&KVs[sr][sh + i * 8] =
          *(const uint4*)&Vb[(size_t)sr * 2048 + kv0 + sh + i * 8];
    __syncthreads();

    // O += P V  (A = P from Ps, B = V^T tile: [d][kv] contiguous kv)
#pragma unroll
    for (int kk = 0; kk < 4; ++kk) {
      short8 pf = *(const short8*)&Ps[wave * 16 + l16][kk * 32 + quad * 8];
#pragma unroll
      for (int jd = 0; jd < 8; ++jd) {
        short8 vb = *(const short8*)&KVs[jd * 16 + l16][kk * 32 + quad * 8];
        of[jd] = __builtin_amdgcn_mfma_f32_16x16x32_bf16(pf, vb, of[jd], 0, 0, 0);
      }
    }
  }

#pragma unroll
  for (int r = 0; r < 4; ++r) {
    const float inv = 1.f / l_r[r];
    const size_t row = qr0 + quad * 4 + r;
#pragma unroll
    for (int jd = 0; jd < 8; ++jd)
      Ob[row * 2048 + jd * 16 + l16] = f2bf(of[jd][r] * inv);
  }
}

// ---------------------------------------------------------------------------
extern "C" void kernel_launch(void* const* d_in, const int* in_sizes, int n_in,
                              void* d_out, int out_size, void* d_ws, size_t ws_size,
                              hipStream_t stream) {
  const float* x       = (const float*)d_in[0];  // (2,2048,2048)
  const float* latents = (const float*)d_in[1];  // (2,2048,3072)
  const float* w_q     = (const float*)d_in[2];  // (3072,2048)
  const float* w_kv    = (const float*)d_in[3];  // (2048,4096)
  const float* w_out   = (const float*)d_in[4];  // (2048,3072)
  const float* ln1_g   = (const float*)d_in[5];
  const float* ln1_b   = (const float*)d_in[6];
  const float* ln2_g   = (const float*)d_in[7];
  const float* ln2_b   = (const float*)d_in[8];

  char* ws = (char*)d_ws;
  // workspace layout (134,217,728 B total), with lifetime-based aliasing:
  u16* xn    = (u16*)(ws);              // 16.8 MB  LN(x)        [dead after kv gemm]
  u16* lnl   = (u16*)(ws + 16777216);   // 25.2 MB  LN(latents)  [dead after q gemm]
  u16* wqT   = (u16*)(ws + 41943040);   // 12.6 MB
  u16* wkvT  = (u16*)(ws + 54525952);   // 16.8 MB
  u16* woutT = (u16*)(ws + 71303168);   // 12.6 MB
  u16* qb    = (u16*)(ws + 83886080);   // 16.8 MB
  u16* kvb   = (u16*)(ws + 100663296);  // 33.6 MB
  u16* vTb   = lnl;                     // alias: vT written after lnl is dead
  u16* attn  = xn;                      // alias: attn-out written after xn is dead

  ln_cast<2048><<<dim3(4096), 256, 0, stream>>>(x, ln1_g, ln1_b, xn);
  ln_cast<3072><<<dim3(4096), 256, 0, stream>>>(latents, ln2_g, ln2_b, lnl);

  transpose_cast<<<dim3(64, 96), dim3(32, 8), 0, stream>>>(w_q, wqT, 3072, 2048);
  transpose_cast<<<dim3(128, 64), dim3(32, 8), 0, stream>>>(w_kv, wkvT, 2048, 4096);
  transpose_cast<<<dim3(96, 64), dim3(32, 8), 0, stream>>>(w_out, woutT, 2048, 3072);

  // q = LN(latents) @ w_q        (4096 x 2048, K=3072)
  gemm_bt<u16><<<dim3(16, 32), 256, 0, stream>>>(lnl, wqT, qb, 4096, 2048, 3072);
  // kv = LN(x) @ w_kv            (4096 x 4096, K=2048)
  gemm_bt<u16><<<dim3(32, 32), 256, 0, stream>>>(xn, wkvT, kvb, 4096, 4096, 2048);

  transpose_v<<<dim3(4, 64, 32), dim3(32, 8), 0, stream>>>(kvb, vTb);

  flash_attn<<<dim3(32, 32), 256, 0, stream>>>(qb, kvb, vTb, attn);

  // out = attn @ w_out           (4096 x 3072, K=2048) -> fp32 d_out
  gemm_bt<float><<<dim3(24, 32), 256, 0, stream>>>(attn, woutT, (float*)d_out, 4096, 3072, 2048);
}

// Round 3
// 617.480 us; speedup vs baseline: 1.2901x; 1.2901x over previous
//
#include <hip/hip_runtime.h>
#include <type_traits>

// PerceiverAttentionCA on MI355X (gfx950).  Round 3:
// Round-2 design with ONE fix: flash PV read of Vs used row stride 128,
// but Vs is 128 rows x 64 u16 (stride 64).  All other swizzles verified
// by concrete index simulation.

using u16 = unsigned short;
using u32 = unsigned int;
typedef __attribute__((ext_vector_type(8))) short short8;   // 8 x bf16 bits
typedef __attribute__((ext_vector_type(4))) float floatx4;  // MFMA accumulator

typedef __attribute__((address_space(1))) const unsigned int gu32;
typedef __attribute__((address_space(3))) unsigned int lu32;

__device__ __forceinline__ void gld16(void* lds, const void* g) {
  __builtin_amdgcn_global_load_lds((gu32*)g, (lu32*)lds, 16, 0, 0);
}

__device__ inline u16 f2bf(float f) {
  u32 u = __float_as_uint(f);
  u32 r = (u + 0x7FFFu + ((u >> 16) & 1u)) >> 16;   // RNE
  return (u16)r;
}

// ---------------------------------------------------------------------------
// LayerNorm + cast to bf16.  One block (256 thr) per row.  L in {2048, 3072}.
// ---------------------------------------------------------------------------
template <int L>
__global__ __launch_bounds__(256) void ln_cast(const float* __restrict__ in,
                                               const float* __restrict__ gw,
                                               const float* __restrict__ bw,
                                               u16* __restrict__ out) {
  constexpr int C4 = L / 1024;
  const int row = blockIdx.x;
  const int t = threadIdx.x;
  const float* rp = in + (size_t)row * L;
  float4 v[C4];
  float s = 0.f, ss = 0.f;
#pragma unroll
  for (int c = 0; c < C4; ++c) {
    v[c] = *(const float4*)(rp + (c * 256 + t) * 4);
    s += v[c].x + v[c].y + v[c].z + v[c].w;
    ss += v[c].x * v[c].x + v[c].y * v[c].y + v[c].z * v[c].z + v[c].w * v[c].w;
  }
#pragma unroll
  for (int off = 32; off > 0; off >>= 1) {
    s += __shfl_down(s, off);
    ss += __shfl_down(ss, off);
  }
  __shared__ float red[8];
  const int wave = t >> 6, lane = t & 63;
  if (lane == 0) { red[wave] = s; red[4 + wave] = ss; }
  __syncthreads();
  const float tot = red[0] + red[1] + red[2] + red[3];
  const float tss = red[4] + red[5] + red[6] + red[7];
  const float mu = tot * (1.f / L);
  const float rstd = rsqrtf(tss * (1.f / L) - mu * mu + 1e-5f);
  u16* op = out + (size_t)row * L;
#pragma unroll
  for (int c = 0; c < C4; ++c) {
    const int base = (c * 256 + t) * 4;
    float4 gv = *(const float4*)(gw + base);
    float4 bv = *(const float4*)(bw + base);
    u32 p0 = (u32)f2bf((v[c].x - mu) * rstd * gv.x + bv.x) |
             ((u32)f2bf((v[c].y - mu) * rstd * gv.y + bv.y) << 16);
    u32 p1 = (u32)f2bf((v[c].z - mu) * rstd * gv.z + bv.z) |
             ((u32)f2bf((v[c].w - mu) * rstd * gv.w + bv.w) << 16);
    uint2 pk; pk.x = p0; pk.y = p1;
    *(uint2*)(op + base) = pk;
  }
}

// ---------------------------------------------------------------------------
// Transpose + cast: fp32 in (R x C) -> bf16 out (C x R).  Block (32,8).
// ---------------------------------------------------------------------------
__global__ __launch_bounds__(256) void transpose_cast(const float* __restrict__ in,
                                                      u16* __restrict__ out,
                                                      int R, int C) {
  __shared__ u16 tile[32][33];
  const int c0 = blockIdx.x * 32, r0 = blockIdx.y * 32;
  const int x = threadIdx.x, y = threadIdx.y;
#pragma unroll
  for (int j = 0; j < 4; ++j)
    tile[y + 8 * j][x] = f2bf(in[(size_t)(r0 + y + 8 * j) * C + c0 + x]);
  __syncthreads();
#pragma unroll
  for (int j = 0; j < 4; ++j)
    out[(size_t)(c0 + y + 8 * j) * R + r0 + x] = tile[x][y + 8 * j];
}

// ---------------------------------------------------------------------------
// Extract+transpose V from kv buffer -> vT (b,h,128,2048).
// ---------------------------------------------------------------------------
__global__ __launch_bounds__(256) void transpose_v(const u16* __restrict__ kvb,
                                                   u16* __restrict__ vT) {
  __shared__ u16 tile[32][33];
  const int bh = blockIdx.z, b = bh >> 4, h = bh & 15;
  const u16* src = kvb + (size_t)b * 2048 * 4096 + 2048 + h * 128;
  u16* dst = vT + (size_t)bh * 128 * 2048;
  const int d0 = blockIdx.x * 32, n0 = blockIdx.y * 32;
  const int x = threadIdx.x, y = threadIdx.y;
#pragma unroll
  for (int j = 0; j < 4; ++j)
    tile[y + 8 * j][x] = src[(size_t)(n0 + y + 8 * j) * 4096 + d0 + x];
  __syncthreads();
#pragma unroll
  for (int j = 0; j < 4; ++j)
    dst[(size_t)(d0 + y + 8 * j) * 2048 + n0 + x] = tile[x][y + 8 * j];
}

// ---------------------------------------------------------------------------
// GEMM  C(MxN) = A(MxK) * Bt(NxK)^T.  m97 structure: global_load_lds width=16
// into unpadded [128][32] tiles, chunk-swizzle db^((row>>1)&3) (2-way banks).
// ---------------------------------------------------------------------------
template <typename OutT>
__global__ __launch_bounds__(256) void gemm_bt(const u16* __restrict__ A,
                                               const u16* __restrict__ Bt,
                                               OutT* __restrict__ C,
                                               int M, int N, int K) {
  __shared__ u16 As[128 * 32];
  __shared__ u16 Bs[128 * 32];
  const int tid = threadIdx.x;
  const int wave = tid >> 6, lane = tid & 63, l16 = lane & 15, quad = lane >> 4;
  const int wm = (wave >> 1) * 64, wn = (wave & 1) * 64;
  const long m0 = (long)blockIdx.y * 128, n0 = (long)blockIdx.x * 128;
  const int srow = tid >> 2;
  const int sdb = (tid & 3) ^ ((tid >> 3) & 3);
  const u16* Ag0 = A + (m0 + srow) * (long)K + sdb * 8;
  const u16* Bg0 = Bt + (n0 + srow) * (long)K + sdb * 8;
  u16* Al0 = &As[tid * 8];       u16* Al1 = &As[(tid + 256) * 8];
  u16* Bl0 = &Bs[tid * 8];       u16* Bl1 = &Bs[(tid + 256) * 8];
  const long rowoff = 64L * K;

  const floatx4 fz = {0.f, 0.f, 0.f, 0.f};
  floatx4 acc[4][4];
#pragma unroll
  for (int i = 0; i < 4; ++i)
#pragma unroll
    for (int j = 0; j < 4; ++j) acc[i][j] = fz;

  const int sw = (quad ^ ((l16 >> 1) & 3)) * 8;  // swizzled frag chunk offset

  for (int k0 = 0; k0 < K; k0 += 32) {
    __syncthreads();
    gld16(Al0, Ag0 + k0);
    gld16(Al1, Ag0 + rowoff + k0);
    gld16(Bl0, Bg0 + k0);
    gld16(Bl1, Bg0 + rowoff + k0);
    __syncthreads();
    short8 a[4], b[4];
#pragma unroll
    for (int i = 0; i < 4; ++i) a[i] = *(const short8*)&As[(wm + i * 16 + l16) * 32 + sw];
#pragma unroll
    for (int j = 0; j < 4; ++j) b[j] = *(const short8*)&Bs[(wn + j * 16 + l16) * 32 + sw];
#pragma unroll
    for (int i = 0; i < 4; ++i)
#pragma unroll
      for (int j = 0; j < 4; ++j)
        acc[i][j] = __builtin_amdgcn_mfma_f32_16x16x32_bf16(a[i], b[j], acc[i][j], 0, 0, 0);
  }

#pragma unroll
  for (int i = 0; i < 4; ++i)
#pragma unroll
    for (int r = 0; r < 4; ++r) {
      const long row = m0 + wm + i * 16 + quad * 4 + r;
#pragma unroll
      for (int j = 0; j < 4; ++j) {
        const long col = n0 + wn + j * 16 + l16;
        if constexpr (std::is_same<OutT, float>::value)
          C[row * N + col] = acc[i][j][r];
        else
          C[row * N + col] = f2bf(acc[i][j][r]);
      }
    }
}

// ---------------------------------------------------------------------------
// Flash attention v2.  Grid (2048/128, b*h) = (16,32).  Block 256 = 4 waves,
// 32 q-rows/wave.  kv-tile 64.  LDS 48 KB (2 blocks/CU).
// ---------------------------------------------------------------------------
__global__ __launch_bounds__(256, 2) void flash_attn(const u16* __restrict__ Q,
                                                     const u16* __restrict__ KV,
                                                     const u16* __restrict__ VT,
                                                     u16* __restrict__ O) {
  __shared__ u16 Ks[64 * 128];       // [kv][16 chunks], chunk^= (kv&15)
  __shared__ u16 Vs[128 * 64];       // [d][8 chunks],   chunk^= (d&7)
  __shared__ u16 Ps[4][32 * 64];     // per-wave [q][8 chunks], chunk^=((q&7)^(q>>3))
  const int tid = threadIdx.x;
  const int wave = tid >> 6, lane = tid & 63, l16 = lane & 15, quad = lane >> 4;
  const int bh = blockIdx.y, b = bh >> 4, h = bh & 15;
  const u16* Qb = Q + (size_t)b * 2048 * 2048 + h * 128;
  const u16* Kb = KV + (size_t)b * 2048 * 4096 + h * 128;
  const u16* Vb = VT + (size_t)bh * 128 * 2048;
  u16* Ob = O + (size_t)b * 2048 * 2048 + h * 128;
  const int q0 = blockIdx.x * 128 + wave * 32;

  short8 qf[2][4];
#pragma unroll
  for (int t = 0; t < 2; ++t)
#pragma unroll
    for (int kd = 0; kd < 4; ++kd)
      qf[t][kd] = *(const short8*)&Qb[(size_t)(q0 + t * 16 + l16) * 2048 + kd * 32 + quad * 8];

  short8 onesf;
  {
    union { short8 s; u32 w[4]; } uo;
    const u32 o = (l16 == 0) ? 0x3F803F80u : 0u;
#pragma unroll
    for (int i = 0; i < 4; ++i) uo.w[i] = o;
    onesf = uo.s;
  }

  const floatx4 fz = {0.f, 0.f, 0.f, 0.f};
  floatx4 oacc[2][9];
  float m[2][4];
#pragma unroll
  for (int t = 0; t < 2; ++t) {
#pragma unroll
    for (int jd = 0; jd < 9; ++jd) oacc[t][jd] = fz;
#pragma unroll
    for (int r = 0; r < 4; ++r) m[t][r] = -1e30f;
  }

  u16* Psw = Ps[wave];
  const float sc = 0.08838834764831845f;  // 1/sqrt(128)

  for (int kt = 0; kt < 32; ++kt) {
    const int kv0 = kt * 64;
    __syncthreads();  // all waves done with prev K/V tiles
#pragma unroll
    for (int c = 0; c < 4; ++c) {
      const int li = c * 256 + tid;
      const int krow = li >> 4, kdb = (li & 15) ^ (krow & 15);
      gld16(&Ks[li * 8], Kb + (size_t)(kv0 + krow) * 4096 + kdb * 8);
      const int vrow = li >> 3, vdb = (li & 7) ^ (vrow & 7);
      gld16(&Vs[li * 8], Vb + (size_t)vrow * 2048 + kv0 + vdb * 8);
    }
    __syncthreads();  // DMA drained (vmcnt(0) at barrier)

    // S = Q K^T : 2 q-tiles x 4 kv-tiles
    floatx4 sacc[2][4];
#pragma unroll
    for (int t = 0; t < 2; ++t)
#pragma unroll
      for (int jn = 0; jn < 4; ++jn) sacc[t][jn] = fz;
#pragma unroll
    for (int jn = 0; jn < 4; ++jn)
#pragma unroll
      for (int kd = 0; kd < 4; ++kd) {
        short8 kb = *(const short8*)&Ks[(jn * 16 + l16) * 128 + ((4 * kd + quad) ^ l16) * 8];
        sacc[0][jn] = __builtin_amdgcn_mfma_f32_16x16x32_bf16(qf[0][kd], kb, sacc[0][jn], 0, 0, 0);
        sacc[1][jn] = __builtin_amdgcn_mfma_f32_16x16x32_bf16(qf[1][kd], kb, sacc[1][jn], 0, 0, 0);
      }

    // online softmax; write P (bf16) to swizzled LDS
#pragma unroll
    for (int t = 0; t < 2; ++t) {
#pragma unroll
      for (int r = 0; r < 4; ++r) {
        float mx = fmaxf(fmaxf(sacc[t][0][r], sacc[t][1][r]),
                         fmaxf(sacc[t][2][r], sacc[t][3][r]));
#pragma unroll
        for (int off = 8; off > 0; off >>= 1) mx = fmaxf(mx, __shfl_xor(mx, off, 16));
        const float mnew = fmaxf(m[t][r], sc * mx);
        const float alpha = __expf(m[t][r] - mnew);
        m[t][r] = mnew;
        const int q = t * 16 + quad * 4 + r;               // 0..31
        const int mask = (q & 7) ^ (q >> 3);
        u16* prow = &Psw[q * 64 + (l16 & 7)];
#pragma unroll
        for (int jn = 0; jn < 4; ++jn) {
          const float p = __expf(sc * sacc[t][jn][r] - mnew);
          const int slot = (2 * jn + (l16 >> 3)) ^ mask;
          prow[slot * 8] = f2bf(p);
        }
#pragma unroll
        for (int jd = 0; jd < 9; ++jd) oacc[t][jd][r] *= alpha;
      }
    }

    // O += P V   (A = P frags from Ps, B = V frags from Vs; +ones col)
    const int pmask0 = (l16 & 7) ^ (l16 >> 3);        // t=0
    const int pmask1 = (l16 & 7) ^ (2 + (l16 >> 3));  // t=1
#pragma unroll
    for (int kk = 0; kk < 2; ++kk) {
      const int chunk = 4 * kk + quad;
      short8 pf0 = *(const short8*)&Psw[(l16) * 64 + (chunk ^ pmask0) * 8];
      short8 pf1 = *(const short8*)&Psw[(16 + l16) * 64 + (chunk ^ pmask1) * 8];
#pragma unroll
      for (int jd = 0; jd < 8; ++jd) {
        short8 vb = *(const short8*)&Vs[(jd * 16 + l16) * 64 + (chunk ^ (l16 & 7)) * 8];
        oacc[0][jd] = __builtin_amdgcn_mfma_f32_16x16x32_bf16(pf0, vb, oacc[0][jd], 0, 0, 0);
        oacc[1][jd] = __builtin_amdgcn_mfma_f32_16x16x32_bf16(pf1, vb, oacc[1][jd], 0, 0, 0);
      }
      oacc[0][8] = __builtin_amdgcn_mfma_f32_16x16x32_bf16(pf0, onesf, oacc[0][8], 0, 0, 0);
      oacc[1][8] = __builtin_amdgcn_mfma_f32_16x16x32_bf16(pf1, onesf, oacc[1][8], 0, 0, 0);
    }
  }

  // epilogue: l from ones-column (lane quad*16, reg r); divide, store
#pragma unroll
  for (int t = 0; t < 2; ++t)
#pragma unroll
    for (int r = 0; r < 4; ++r) {
      const float l = __shfl(oacc[t][8][r], lane & 48);
      const float inv = 1.f / l;
      const size_t row = q0 + t * 16 + quad * 4 + r;
#pragma unroll
      for (int jd = 0; jd < 8; ++jd)
        Ob[row * 2048 + jd * 16 + l16] = f2bf(oacc[t][jd][r] * inv);
    }
}

// ---------------------------------------------------------------------------
extern "C" void kernel_launch(void* const* d_in, const int* in_sizes, int n_in,
                              void* d_out, int out_size, void* d_ws, size_t ws_size,
                              hipStream_t stream) {
  const float* x       = (const float*)d_in[0];
  const float* latents = (const float*)d_in[1];
  const float* w_q     = (const float*)d_in[2];
  const float* w_kv    = (const float*)d_in[3];
  const float* w_out   = (const float*)d_in[4];
  const float* ln1_g   = (const float*)d_in[5];
  const float* ln1_b   = (const float*)d_in[6];
  const float* ln2_g   = (const float*)d_in[7];
  const float* ln2_b   = (const float*)d_in[8];

  char* ws = (char*)d_ws;
  u16* xn    = (u16*)(ws);              // LN(x)        [dead after kv gemm]
  u16* lnl   = (u16*)(ws + 16777216);   // LN(latents)  [dead after q gemm]
  u16* wqT   = (u16*)(ws + 41943040);
  u16* wkvT  = (u16*)(ws + 54525952);
  u16* woutT = (u16*)(ws + 71303168);
  u16* qb    = (u16*)(ws + 83886080);
  u16* kvb   = (u16*)(ws + 100663296);
  u16* vTb   = lnl;                     // alias
  u16* attn  = xn;                      // alias

  ln_cast<2048><<<dim3(4096), 256, 0, stream>>>(x, ln1_g, ln1_b, xn);
  ln_cast<3072><<<dim3(4096), 256, 0, stream>>>(latents, ln2_g, ln2_b, lnl);

  transpose_cast<<<dim3(64, 96), dim3(32, 8), 0, stream>>>(w_q, wqT, 3072, 2048);
  transpose_cast<<<dim3(128, 64), dim3(32, 8), 0, stream>>>(w_kv, wkvT, 2048, 4096);
  transpose_cast<<<dim3(96, 64), dim3(32, 8), 0, stream>>>(w_out, woutT, 2048, 3072);

  gemm_bt<u16><<<dim3(16, 32), 256, 0, stream>>>(lnl, wqT, qb, 4096, 2048, 3072);
  gemm_bt<u16><<<dim3(32, 32), 256, 0, stream>>>(xn, wkvT, kvb, 4096, 4096, 2048);

  transpose_v<<<dim3(4, 64, 32), dim3(32, 8), 0, stream>>>(kvb, vTb);

  flash_attn<<<dim3(16, 32), 256, 0, stream>>>(qb, kvb, vTb, attn);

  gemm_bt<float><<<dim3(24, 32), 256, 0, stream>>>(attn, woutT, (float*)d_out, 4096, 3072, 2048);
}

// Round 4
// 572.552 us; speedup vs baseline: 1.3913x; 1.0785x over previous
//
#include <hip/hip_runtime.h>
#include <type_traits>

// PerceiverAttentionCA on MI355X (gfx950).  Round 4:
//  - flash_attn: double-buffered K/V staging (1 barrier/kv-tile, drain hidden
//    behind compute), XCD head-clustering grid swizzle, exp2-space softmax.
//  - gemm_bt: BK=64 (half the barriers, 32 KB LDS, same DMA volume).

using u16 = unsigned short;
using u32 = unsigned int;
typedef __attribute__((ext_vector_type(8))) short short8;   // 8 x bf16 bits
typedef __attribute__((ext_vector_type(4))) float floatx4;  // MFMA accumulator

typedef __attribute__((address_space(1))) const unsigned int gu32;
typedef __attribute__((address_space(3))) unsigned int lu32;

__device__ __forceinline__ void gld16(void* lds, const void* g) {
  __builtin_amdgcn_global_load_lds((gu32*)g, (lu32*)lds, 16, 0, 0);
}

__device__ inline u16 f2bf(float f) {
  u32 u = __float_as_uint(f);
  u32 r = (u + 0x7FFFu + ((u >> 16) & 1u)) >> 16;   // RNE
  return (u16)r;
}

// ---------------------------------------------------------------------------
// LayerNorm + cast to bf16.  One block (256 thr) per row.  L in {2048, 3072}.
// ---------------------------------------------------------------------------
template <int L>
__global__ __launch_bounds__(256) void ln_cast(const float* __restrict__ in,
                                               const float* __restrict__ gw,
                                               const float* __restrict__ bw,
                                               u16* __restrict__ out) {
  constexpr int C4 = L / 1024;
  const int row = blockIdx.x;
  const int t = threadIdx.x;
  const float* rp = in + (size_t)row * L;
  float4 v[C4];
  float s = 0.f, ss = 0.f;
#pragma unroll
  for (int c = 0; c < C4; ++c) {
    v[c] = *(const float4*)(rp + (c * 256 + t) * 4);
    s += v[c].x + v[c].y + v[c].z + v[c].w;
    ss += v[c].x * v[c].x + v[c].y * v[c].y + v[c].z * v[c].z + v[c].w * v[c].w;
  }
#pragma unroll
  for (int off = 32; off > 0; off >>= 1) {
    s += __shfl_down(s, off);
    ss += __shfl_down(ss, off);
  }
  __shared__ float red[8];
  const int wave = t >> 6, lane = t & 63;
  if (lane == 0) { red[wave] = s; red[4 + wave] = ss; }
  __syncthreads();
  const float tot = red[0] + red[1] + red[2] + red[3];
  const float tss = red[4] + red[5] + red[6] + red[7];
  const float mu = tot * (1.f / L);
  const float rstd = rsqrtf(tss * (1.f / L) - mu * mu + 1e-5f);
  u16* op = out + (size_t)row * L;
#pragma unroll
  for (int c = 0; c < C4; ++c) {
    const int base = (c * 256 + t) * 4;
    float4 gv = *(const float4*)(gw + base);
    float4 bv = *(const float4*)(bw + base);
    u32 p0 = (u32)f2bf((v[c].x - mu) * rstd * gv.x + bv.x) |
             ((u32)f2bf((v[c].y - mu) * rstd * gv.y + bv.y) << 16);
    u32 p1 = (u32)f2bf((v[c].z - mu) * rstd * gv.z + bv.z) |
             ((u32)f2bf((v[c].w - mu) * rstd * gv.w + bv.w) << 16);
    uint2 pk; pk.x = p0; pk.y = p1;
    *(uint2*)(op + base) = pk;
  }
}

// ---------------------------------------------------------------------------
// Transpose + cast: fp32 in (R x C) -> bf16 out (C x R).  Block (32,8).
// ---------------------------------------------------------------------------
__global__ __launch_bounds__(256) void transpose_cast(const float* __restrict__ in,
                                                      u16* __restrict__ out,
                                                      int R, int C) {
  __shared__ u16 tile[32][33];
  const int c0 = blockIdx.x * 32, r0 = blockIdx.y * 32;
  const int x = threadIdx.x, y = threadIdx.y;
#pragma unroll
  for (int j = 0; j < 4; ++j)
    tile[y + 8 * j][x] = f2bf(in[(size_t)(r0 + y + 8 * j) * C + c0 + x]);
  __syncthreads();
#pragma unroll
  for (int j = 0; j < 4; ++j)
    out[(size_t)(c0 + y + 8 * j) * R + r0 + x] = tile[x][y + 8 * j];
}

// ---------------------------------------------------------------------------
// Extract+transpose V from kv buffer -> vT (b,h,128,2048).
// ---------------------------------------------------------------------------
__global__ __launch_bounds__(256) void transpose_v(const u16* __restrict__ kvb,
                                                   u16* __restrict__ vT) {
  __shared__ u16 tile[32][33];
  const int bh = blockIdx.z, b = bh >> 4, h = bh & 15;
  const u16* src = kvb + (size_t)b * 2048 * 4096 + 2048 + h * 128;
  u16* dst = vT + (size_t)bh * 128 * 2048;
  const int d0 = blockIdx.x * 32, n0 = blockIdx.y * 32;
  const int x = threadIdx.x, y = threadIdx.y;
#pragma unroll
  for (int j = 0; j < 4; ++j)
    tile[y + 8 * j][x] = src[(size_t)(n0 + y + 8 * j) * 4096 + d0 + x];
  __syncthreads();
#pragma unroll
  for (int j = 0; j < 4; ++j)
    dst[(size_t)(d0 + y + 8 * j) * 2048 + n0 + x] = tile[x][y + 8 * j];
}

// ---------------------------------------------------------------------------
// GEMM  C(MxN) = A(MxK) * Bt(NxK)^T.  BK=64: global_load_lds width=16 into
// [128][64] tiles (32 KB), chunk-swizzle slot = chunk ^ (row&7) (2-way banks),
// half the barriers of BK=32.
// ---------------------------------------------------------------------------
template <typename OutT>
__global__ __launch_bounds__(256) void gemm_bt(const u16* __restrict__ A,
                                               const u16* __restrict__ Bt,
                                               OutT* __restrict__ C,
                                               int M, int N, int K) {
  __shared__ u16 As[128 * 64];
  __shared__ u16 Bs[128 * 64];
  const int tid = threadIdx.x;
  const int wave = tid >> 6, lane = tid & 63, l16 = lane & 15, quad = lane >> 4;
  const int wm = (wave >> 1) * 64, wn = (wave & 1) * 64;
  const long m0 = (long)blockIdx.y * 128, n0 = (long)blockIdx.x * 128;
  // staging: 4 chunks/thread/matrix: li = c*256+tid -> row = c*32 + (tid>>3),
  // lds slot = tid&7, global chunk = slot ^ (row&7) = (tid&7)^((tid>>3)&7)
  const int srow = tid >> 3;                          // 0..31
  const int gc = ((tid & 7) ^ ((tid >> 3) & 7)) * 8;  // u16 offset
  const u16* Ag0 = A + (m0 + srow) * (long)K + gc;
  const u16* Bg0 = Bt + (n0 + srow) * (long)K + gc;
  const long rowoff = 32L * K;

  const floatx4 fz = {0.f, 0.f, 0.f, 0.f};
  floatx4 acc[4][4];
#pragma unroll
  for (int i = 0; i < 4; ++i)
#pragma unroll
    for (int j = 0; j < 4; ++j) acc[i][j] = fz;

  for (int k0 = 0; k0 < K; k0 += 64) {
    __syncthreads();
#pragma unroll
    for (int c = 0; c < 4; ++c) {
      gld16(&As[(c * 256 + tid) * 8], Ag0 + c * rowoff + k0);
      gld16(&Bs[(c * 256 + tid) * 8], Bg0 + c * rowoff + k0);
    }
    __syncthreads();
#pragma unroll
    for (int kd = 0; kd < 2; ++kd) {
      const int sw = ((4 * kd + quad) ^ (l16 & 7)) * 8;
      short8 a[4], b[4];
#pragma unroll
      for (int i = 0; i < 4; ++i) a[i] = *(const short8*)&As[(wm + i * 16 + l16) * 64 + sw];
#pragma unroll
      for (int j = 0; j < 4; ++j) b[j] = *(const short8*)&Bs[(wn + j * 16 + l16) * 64 + sw];
#pragma unroll
      for (int i = 0; i < 4; ++i)
#pragma unroll
        for (int j = 0; j < 4; ++j)
          acc[i][j] = __builtin_amdgcn_mfma_f32_16x16x32_bf16(a[i], b[j], acc[i][j], 0, 0, 0);
    }
  }

#pragma unroll
  for (int i = 0; i < 4; ++i)
#pragma unroll
    for (int r = 0; r < 4; ++r) {
      const long row = m0 + wm + i * 16 + quad * 4 + r;
#pragma unroll
      for (int j = 0; j < 4; ++j) {
        const long col = n0 + wn + j * 16 + l16;
        if constexpr (std::is_same<OutT, float>::value)
          C[row * N + col] = acc[i][j][r];
        else
          C[row * N + col] = f2bf(acc[i][j][r]);
      }
    }
}

// ---------------------------------------------------------------------------
// Flash attention v3.  Grid 512 blocks (XCD head-clustered), 4 waves,
// 32 q-rows/wave, kv-tile 64, DOUBLE-BUFFERED K/V (80 KB LDS, 2 blocks/CU).
// exp2-space online softmax; row-sum via ones-column MFMA.
// ---------------------------------------------------------------------------
__global__ __launch_bounds__(256, 2) void flash_attn(const u16* __restrict__ Q,
                                                     const u16* __restrict__ KV,
                                                     const u16* __restrict__ VT,
                                                     u16* __restrict__ O) {
  __shared__ u16 Ks[2][64 * 128];    // [kv][16 chunks], chunk^= (kv&15)
  __shared__ u16 Vs[2][128 * 64];    // [d][8 chunks],   chunk^= (d&7)
  __shared__ u16 Ps[4][32 * 64];     // per-wave [q][8 chunks], chunk^=((q&7)^(q>>3))
  const int tid = threadIdx.x;
  const int wave = tid >> 6, lane = tid & 63, l16 = lane & 15, quad = lane >> 4;
  // XCD head clustering: blocks with the same bh land on the same XCD (d%8).
  const int d = blockIdx.x;
  const int bh = (d & 7) * 4 + ((d >> 3) & 3);
  const int qt = d >> 5;
  const int b = bh >> 4, h = bh & 15;
  const u16* Qb = Q + (size_t)b * 2048 * 2048 + h * 128;
  const u16* Kb = KV + (size_t)b * 2048 * 4096 + h * 128;
  const u16* Vb = VT + (size_t)bh * 128 * 2048;
  u16* Ob = O + (size_t)b * 2048 * 2048 + h * 128;
  const int q0 = qt * 128 + wave * 32;

  short8 qf[2][4];
#pragma unroll
  for (int t = 0; t < 2; ++t)
#pragma unroll
    for (int kd = 0; kd < 4; ++kd)
      qf[t][kd] = *(const short8*)&Qb[(size_t)(q0 + t * 16 + l16) * 2048 + kd * 32 + quad * 8];

  short8 onesf;
  {
    union { short8 s; u32 w[4]; } uo;
    const u32 o = (l16 == 0) ? 0x3F803F80u : 0u;
#pragma unroll
    for (int i = 0; i < 4; ++i) uo.w[i] = o;
    onesf = uo.s;
  }

  const floatx4 fz = {0.f, 0.f, 0.f, 0.f};
  floatx4 oacc[2][9];
  float m[2][4];
#pragma unroll
  for (int t = 0; t < 2; ++t) {
#pragma unroll
    for (int jd = 0; jd < 9; ++jd) oacc[t][jd] = fz;
#pragma unroll
    for (int r = 0; r < 4; ++r) m[t][r] = -1e30f;
  }

  u16* Psw = Ps[wave];
  const float sc2 = 0.12751775f;  // (1/sqrt(128)) * log2(e)

  auto stage = [&](int buf, int kv0) {
#pragma unroll
    for (int c = 0; c < 4; ++c) {
      const int li = c * 256 + tid;
      const int krow = li >> 4, kdb = (li & 15) ^ (krow & 15);
      gld16(&Ks[buf][li * 8], Kb + (size_t)(kv0 + krow) * 4096 + kdb * 8);
      const int vrow = li >> 3, vdb = (li & 7) ^ (vrow & 7);
      gld16(&Vs[buf][li * 8], Vb + (size_t)vrow * 2048 + kv0 + vdb * 8);
    }
  };

  stage(0, 0);
  int cur = 0;

  for (int kt = 0; kt < 32; ++kt) {
    __syncthreads();  // drains DMA for buf[cur]; syncs prev compute on buf[cur^1]
    if (kt < 31) stage(cur ^ 1, (kt + 1) * 64);
    const u16* Kc = Ks[cur];
    const u16* Vc = Vs[cur];

    // S = Q K^T : 2 q-tiles x 4 kv-tiles
    floatx4 sacc[2][4];
#pragma unroll
    for (int t = 0; t < 2; ++t)
#pragma unroll
      for (int jn = 0; jn < 4; ++jn) sacc[t][jn] = fz;
#pragma unroll
    for (int jn = 0; jn < 4; ++jn)
#pragma unroll
      for (int kd = 0; kd < 4; ++kd) {
        short8 kb = *(const short8*)&Kc[(jn * 16 + l16) * 128 + ((4 * kd + quad) ^ l16) * 8];
        sacc[0][jn] = __builtin_amdgcn_mfma_f32_16x16x32_bf16(qf[0][kd], kb, sacc[0][jn], 0, 0, 0);
        sacc[1][jn] = __builtin_amdgcn_mfma_f32_16x16x32_bf16(qf[1][kd], kb, sacc[1][jn], 0, 0, 0);
      }

    // online softmax in exp2 space; write P (bf16) to swizzled LDS
#pragma unroll
    for (int t = 0; t < 2; ++t) {
#pragma unroll
      for (int r = 0; r < 4; ++r) {
        float mx = fmaxf(fmaxf(sacc[t][0][r], sacc[t][1][r]),
                         fmaxf(sacc[t][2][r], sacc[t][3][r]));
#pragma unroll
        for (int off = 8; off > 0; off >>= 1) mx = fmaxf(mx, __shfl_xor(mx, off, 16));
        const float mnew = fmaxf(m[t][r], sc2 * mx);
        const float alpha = __builtin_amdgcn_exp2f(m[t][r] - mnew);
        m[t][r] = mnew;
        const int q = t * 16 + quad * 4 + r;               // 0..31
        const int mask = (q & 7) ^ (q >> 3);
        u16* prow = &Psw[q * 64 + (l16 & 7)];
#pragma unroll
        for (int jn = 0; jn < 4; ++jn) {
          const float p = __builtin_amdgcn_exp2f(fmaf(sc2, sacc[t][jn][r], -mnew));
          const int slot = (2 * jn + (l16 >> 3)) ^ mask;
          prow[slot * 8] = f2bf(p);
        }
#pragma unroll
        for (int jd = 0; jd < 9; ++jd) oacc[t][jd][r] *= alpha;
      }
    }

    // O += P V   (A = P frags from Ps, B = V frags from Vs; +ones col)
    const int pmask0 = (l16 & 7) ^ (l16 >> 3);        // t=0
    const int pmask1 = (l16 & 7) ^ (2 + (l16 >> 3));  // t=1
#pragma unroll
    for (int kk = 0; kk < 2; ++kk) {
      const int chunk = 4 * kk + quad;
      short8 pf0 = *(const short8*)&Psw[(l16) * 64 + (chunk ^ pmask0) * 8];
      short8 pf1 = *(const short8*)&Psw[(16 + l16) * 64 + (chunk ^ pmask1) * 8];
#pragma unroll
      for (int jd = 0; jd < 8; ++jd) {
        short8 vb = *(const short8*)&Vc[(jd * 16 + l16) * 64 + (chunk ^ (l16 & 7)) * 8];
        oacc[0][jd] = __builtin_amdgcn_mfma_f32_16x16x32_bf16(pf0, vb, oacc[0][jd], 0, 0, 0);
        oacc[1][jd] = __builtin_amdgcn_mfma_f32_16x16x32_bf16(pf1, vb, oacc[1][jd], 0, 0, 0);
      }
      oacc[0][8] = __builtin_amdgcn_mfma_f32_16x16x32_bf16(pf0, onesf, oacc[0][8], 0, 0, 0);
      oacc[1][8] = __builtin_amdgcn_mfma_f32_16x16x32_bf16(pf1, onesf, oacc[1][8], 0, 0, 0);
    }
    cur ^= 1;
  }

  // epilogue: l from ones-column; divide, store
#pragma unroll
  for (int t = 0; t < 2; ++t)
#pragma unroll
    for (int r = 0; r < 4; ++r) {
      const float l = __shfl(oacc[t][8][r], lane & 48);
      const float inv = 1.f / l;
      const size_t row = q0 + t * 16 + quad * 4 + r;
#pragma unroll
      for (int jd = 0; jd < 8; ++jd)
        Ob[row * 2048 + jd * 16 + l16] = f2bf(oacc[t][jd][r] * inv);
    }
}

// ---------------------------------------------------------------------------
extern "C" void kernel_launch(void* const* d_in, const int* in_sizes, int n_in,
                              void* d_out, int out_size, void* d_ws, size_t ws_size,
                              hipStream_t stream) {
  const float* x       = (const float*)d_in[0];
  const float* latents = (const float*)d_in[1];
  const float* w_q     = (const float*)d_in[2];
  const float* w_kv    = (const float*)d_in[3];
  const float* w_out   = (const float*)d_in[4];
  const float* ln1_g   = (const float*)d_in[5];
  const float* ln1_b   = (const float*)d_in[6];
  const float* ln2_g   = (const float*)d_in[7];
  const float* ln2_b   = (const float*)d_in[8];

  char* ws = (char*)d_ws;
  u16* xn    = (u16*)(ws);              // LN(x)        [dead after kv gemm]
  u16* lnl   = (u16*)(ws + 16777216);   // LN(latents)  [dead after q gemm]
  u16* wqT   = (u16*)(ws + 41943040);
  u16* wkvT  = (u16*)(ws + 54525952);
  u16* woutT = (u16*)(ws + 71303168);
  u16* qb    = (u16*)(ws + 83886080);
  u16* kvb   = (u16*)(ws + 100663296);
  u16* vTb   = lnl;                     // alias
  u16* attn  = xn;                      // alias

  ln_cast<2048><<<dim3(4096), 256, 0, stream>>>(x, ln1_g, ln1_b, xn);
  ln_cast<3072><<<dim3(4096), 256, 0, stream>>>(latents, ln2_g, ln2_b, lnl);

  transpose_cast<<<dim3(64, 96), dim3(32, 8), 0, stream>>>(w_q, wqT, 3072, 2048);
  transpose_cast<<<dim3(128, 64), dim3(32, 8), 0, stream>>>(w_kv, wkvT, 2048, 4096);
  transpose_cast<<<dim3(96, 64), dim3(32, 8), 0, stream>>>(w_out, woutT, 2048, 3072);

  gemm_bt<u16><<<dim3(16, 32), 256, 0, stream>>>(lnl, wqT, qb, 4096, 2048, 3072);
  gemm_bt<u16><<<dim3(32, 32), 256, 0, stream>>>(xn, wkvT, kvb, 4096, 4096, 2048);

  transpose_v<<<dim3(4, 64, 32), dim3(32, 8), 0, stream>>>(kvb, vTb);

  flash_attn<<<dim3(512), 256, 0, stream>>>(qb, kvb, vTb, attn);

  gemm_bt<float><<<dim3(24, 32), 256, 0, stream>>>(attn, woutT, (float*)d_out, 4096, 3072, 2048);
}